// Round 19
// baseline (1079.431 us; speedup 1.0000x reference)
//
#include <hip/hip_runtime.h>

#define DEVFN static __device__ __forceinline__

typedef _Float16 f16;
typedef f16 f16x8 __attribute__((ext_vector_type(8)));
typedef f16 f16x4 __attribute__((ext_vector_type(4)));
typedef float f32x4 __attribute__((ext_vector_type(4)));
typedef short short8 __attribute__((ext_vector_type(8)));

constexpr int Bc = 4, Hn = 16, Sn = 2048, DH = 128, Dn = 2048;
constexpr long MROWS = (long)Bc * Sn;  // 8192
constexpr long LDQK = 2 * Dn;          // 4096 (q|k concatenated)

// ---------- MFMA wrapper: dual-signature dispatch (half8 preferred, short8 fallback) ----------
template <typename T, typename C>
DEVFN auto mfma_impl(T a, T b, C c, int)
    -> decltype(__builtin_amdgcn_mfma_f32_16x16x32_f16(a, b, c, 0, 0, 0)) {
  return __builtin_amdgcn_mfma_f32_16x16x32_f16(a, b, c, 0, 0, 0);
}
template <typename T, typename C>
DEVFN C mfma_impl(T a, T b, C c, long) {
  return __builtin_amdgcn_mfma_f32_16x16x32_f16(
      __builtin_bit_cast(short8, a), __builtin_bit_cast(short8, b), c, 0, 0, 0);
}
DEVFN f32x4 MFMA(f16x8 a, f16x8 b, f32x4 c) { return mfma_impl(a, b, c, 0); }

// ---------- non-temporal store helpers (write-once streams; keep L2 for K/V) ----------
DEVFN void nt_store(float* p, float v) { __builtin_nontemporal_store(v, p); }
DEVFN void nt_store4(float* p, f32x4 v) {
  __builtin_nontemporal_store(v, (f32x4*)p);
}

// ---------- async global->LDS 16B ----------
DEVFN void gld_lds16(const f16* g, f16* s) {
  __builtin_amdgcn_global_load_lds(
      (const __attribute__((address_space(1))) unsigned int*)g,
      (__attribute__((address_space(3))) unsigned int*)s, 16, 0, 0);
}

// Stage a 128x64 f16 tile (row stride ld elems) into LDS, linear dest,
// source pre-swizzled so reads with byte^((row&7)<<4) are conflict-free.
DEVFN void stage_tile(const f16* __restrict__ g, long ld, f16* __restrict__ s) {
  const int t = threadIdx.x;
  const int rr = t >> 3;
  const int cb = (t & 7) * 16;  // byte offset within 128B row
#pragma unroll
  for (int ch = 0; ch < 4; ++ch) {
    const int r = ch * 32 + rr;
    const int scb = cb ^ ((r & 7) << 4);
    gld_lds16(g + (long)r * ld + (scb >> 1), s + r * 64 + (cb >> 1));
  }
}

// Stage a 128x128 f16 tile (row stride ld elems), same swizzle, 256B rows, 256 threads.
DEVFN void stage_tile128(const f16* __restrict__ g, long ld, f16* __restrict__ s) {
  const int t = threadIdx.x;
  const int rr = t >> 4;         // 0..15
  const int cb = (t & 15) * 16;  // byte col 0..255
#pragma unroll
  for (int ch = 0; ch < 8; ++ch) {
    const int r = ch * 16 + rr;
    const int scb = cb ^ ((r & 7) << 4);
    gld_lds16(g + (long)r * ld + (scb >> 1), s + r * 128 + (cb >> 1));
  }
}

// Swizzled fragment read: 8 contiguous f16 at (tile-local row, k element), 64-col tile
DEVFN f16x8 ldfrag(const f16* s, int row, int kelem) {
  const int cb = (kelem * 2) ^ ((row & 7) << 4);
  return *(const f16x8*)(s + row * 64 + (cb >> 1));
}

// 128-col f16 tile variant (row stride 256 B)
DEVFN f16x8 ldfrag128(const f16* s, int row, int kelem) {
  const int cb = (kelem * 2) ^ ((row & 7) << 4);
  return *(const f16x8*)((const char*)s + row * 256 + cb);
}

// ---------- all five fp32->f16 converts in ONE launch ----------
// grid (4096, 8): y<4 -> hid quarter y; y=4..7 -> wq/wk/wv/wo
__global__ __launch_bounds__(256) void k_cvt_all(
    const float* __restrict__ hid, const float* __restrict__ wq,
    const float* __restrict__ wk, const float* __restrict__ wv,
    const float* __restrict__ wo, f16* __restrict__ h16,
    f16* __restrict__ wqk16, f16* __restrict__ wv16, f16* __restrict__ wo16) {
  const int y = blockIdx.y;
  const long nW = (long)Dn * Dn;
  const float* x;
  f16* out;
  if (y < 4) {
    x = hid + (long)y * nW;
    out = h16 + (long)y * nW;
  } else if (y == 4) {
    x = wq; out = wqk16;
  } else if (y == 5) {
    x = wk; out = wqk16 + nW;
  } else if (y == 6) {
    x = wv; out = wv16;
  } else {
    x = wo; out = wo16;
  }
  const long i = ((long)blockIdx.x * 256 + threadIdx.x) * 4;
  float4 v = *(const float4*)(x + i);
  f16x4 h;
  h[0] = (f16)v.x; h[1] = (f16)v.y; h[2] = (f16)v.z; h[3] = (f16)v.w;
  *(f16x4*)(out + i) = h;
}

// ---------- GEMM body (C = oscale * A@B^T, f16 out), 2-phase double-buffered LDS ----------
DEVFN void gemm_body(const f16* __restrict__ A, long ldA,
                     const f16* __restrict__ B, long ldB, int K,
                     f16* __restrict__ oh, long ldC, int nt, int mt,
                     float oscale, f16* sA, f16* sB) {
  const int tid = threadIdx.x, w = tid >> 6, lane = tid & 63;
  const int wm = (w >> 1) * 64, wn = (w & 1) * 64;
  const int lr = lane & 15, lg = lane >> 4;
  f32x4 acc[4][4] = {};
  const f16* Ab = A + (long)mt * 128 * ldA;
  const f16* Bb = B + (long)nt * 128 * ldB;

  stage_tile(Ab, ldA, sA);
  stage_tile(Bb, ldB, sB);
  __syncthreads();

  int cur = 0;
  for (int kt = 0; kt < K; kt += 64) {
    if (kt + 64 < K) {
      stage_tile(Ab + kt + 64, ldA, sA + (cur ^ 1) * (128 * 64));
      stage_tile(Bb + kt + 64, ldB, sB + (cur ^ 1) * (128 * 64));
    }
    const f16* cA = sA + cur * (128 * 64);
    const f16* cB = sB + cur * (128 * 64);
#pragma unroll
    for (int kk = 0; kk < 64; kk += 32) {
      f16x8 ahf[4], bhf[4];
#pragma unroll
      for (int m = 0; m < 4; ++m) ahf[m] = ldfrag(cA, wm + m * 16 + lr, kk + lg * 8);
#pragma unroll
      for (int n = 0; n < 4; ++n) bhf[n] = ldfrag(cB, wn + n * 16 + lr, kk + lg * 8);
#pragma unroll
      for (int m = 0; m < 4; ++m)
#pragma unroll
        for (int n = 0; n < 4; ++n) acc[m][n] = MFMA(ahf[m], bhf[n], acc[m][n]);
    }
    __syncthreads();
    cur ^= 1;
  }

#pragma unroll
  for (int m = 0; m < 4; ++m)
#pragma unroll
    for (int n = 0; n < 4; ++n) {
      const int col = nt * 128 + wn + n * 16 + lr;
#pragma unroll
      for (int r = 0; r < 4; ++r) {
        const long row = (long)mt * 128 + wm + m * 16 + lg * 4 + r;
        oh[row * ldC + col] = (f16)(acc[m][n][r] * oscale);
      }
    }
}

// ---------- fused: qk-GEMM (2048 blk) + vT-GEMM (1024 blk) + zfill (1024 blk) ----------
// q columns pre-scaled by log2(e) so k_attn can use raw v_exp (exp2) directly.
__global__ __launch_bounds__(256) void k_fused(
    const f16* __restrict__ h16, const f16* __restrict__ wqk16,
    const f16* __restrict__ wv16, f16* __restrict__ qk16, f16* __restrict__ vT,
    float* __restrict__ wts) {
  __shared__ __align__(16) f16 sA[2 * 128 * 64];
  __shared__ __align__(16) f16 sB[2 * 128 * 64];
  const int bid = blockIdx.x;
  if ((bid & 3) == 3) {
    // ---- zfill role: zero strictly-upper-triangular weight tiles ----
    const int zid = bid >> 2;               // 0..1023
    const int bh = zid & 63, qt = zid >> 6; // 64 x 16
    const int ncols = Sn - (qt + 1) * 128;
    if (ncols <= 0) return;
    float* base = wts + (long)bh * Sn * Sn + (long)qt * 128 * Sn + (qt + 1) * 128;
    const int tid = threadIdx.x;
    const f32x4 z = {0.f, 0.f, 0.f, 0.f};
    for (int r = 0; r < 128; ++r) {
      float* rowp = base + (long)r * Sn;
      for (int c = tid * 4; c < ncols; c += 1024) nt_store4(rowp + c, z);
    }
    return;
  }
  const int gid = 3 * (bid >> 2) + (bid & 3);  // 0..3071
  if (gid < 2048) {
    // ---- qk GEMM: [8192 x 4096] = h16 @ wqk16^T ----
    const int cpx = 2048 >> 3;
    const int swz = (gid & 7) * cpx + (gid >> 3);
    const int nt = swz & 31, mt = swz >> 5;  // 32 x 64
    const float qsc = (nt < 16) ? 1.44269504f : 1.0f;  // log2(e) on q columns
    gemm_body(h16, Dn, wqk16, Dn, Dn, qk16, LDQK, nt, mt, qsc, sA, sB);
  } else {
    // ---- vT GEMM: [2048 x 8192] = wv16 @ h16^T ----
    const int sb = gid - 2048;
    const int cpx = 1024 >> 3;
    const int swz = (sb & 7) * cpx + (sb >> 3);
    const int nt = swz & 63, mt = swz >> 6;  // 64 x 16
    gemm_body(wv16, Dn, h16, Dn, Dn, vT, MROWS, nt, mt, 1.0f, sA, sB);
  }
}

// ---------- WO GEMM: out = ctx @ wo^T + bo (fp32 + bias, NT stores) ----------
__global__ __launch_bounds__(256) void k_gemm_wo(
    const f16* __restrict__ A, const f16* __restrict__ B,
    float* __restrict__ of, const float* __restrict__ bias) {
  const int nwgx = gridDim.x;
  const int nwg = nwgx * gridDim.y;
  const int bid = blockIdx.y * nwgx + blockIdx.x;
  const int cpx = nwg >> 3;
  const int swz = (bid & 7) * cpx + (bid >> 3);
  const int nt = swz % nwgx, mt = swz / nwgx;
  __shared__ __align__(16) f16 sA[2][128 * 64];
  __shared__ __align__(16) f16 sB[2][128 * 64];
  const int tid = threadIdx.x, w = tid >> 6, lane = tid & 63;
  const int wm = (w >> 1) * 64, wn = (w & 1) * 64;
  const int lr = lane & 15, lg = lane >> 4;
  f32x4 acc[4][4] = {};
  const f16* Ab = A + (long)mt * 128 * Dn;
  const f16* Bb = B + (long)nt * 128 * Dn;

  stage_tile(Ab, Dn, sA[0]);
  stage_tile(Bb, Dn, sB[0]);
  __syncthreads();

  int cur = 0;
  for (int kt = 0; kt < Dn; kt += 64) {
    if (kt + 64 < Dn) {
      stage_tile(Ab + kt + 64, Dn, sA[cur ^ 1]);
      stage_tile(Bb + kt + 64, Dn, sB[cur ^ 1]);
    }
#pragma unroll
    for (int kk = 0; kk < 64; kk += 32) {
      f16x8 ahf[4], bhf[4];
#pragma unroll
      for (int m = 0; m < 4; ++m) ahf[m] = ldfrag(sA[cur], wm + m * 16 + lr, kk + lg * 8);
#pragma unroll
      for (int n = 0; n < 4; ++n) bhf[n] = ldfrag(sB[cur], wn + n * 16 + lr, kk + lg * 8);
#pragma unroll
      for (int m = 0; m < 4; ++m)
#pragma unroll
        for (int n = 0; n < 4; ++n) acc[m][n] = MFMA(ahf[m], bhf[n], acc[m][n]);
    }
    __syncthreads();
    cur ^= 1;
  }

#pragma unroll
  for (int m = 0; m < 4; ++m)
#pragma unroll
    for (int n = 0; n < 4; ++n) {
      const int col = nt * 128 + wn + n * 16 + lr;
#pragma unroll
      for (int r = 0; r < 4; ++r) {
        const long row = (long)mt * 128 + wm + m * 16 + lg * 4 + r;
        nt_store(of + row * Dn + col, acc[m][n][r] + bias[col]);
      }
    }
}

// ---------- fused attention, sum-only softmax (exp2, q pre-scaled) ----------
// Ping-pong K buffer, ONE barrier per tile. No LDS P-stash: W is written with
// plain (cacheable) stores and PV reads its A-fragments back from the weights
// one tile behind (wave-own rows; the intervening __syncthreads drains vmcnt,
// so the stores have landed and the lines are L1/L2-hot).
__global__ __launch_bounds__(256) void k_attn(const f16* __restrict__ qk16,
                                              const f16* __restrict__ vT,
                                              float* __restrict__ wts,
                                              f16* __restrict__ ctx) {
  const int wgid = blockIdx.x;
  const int xcd = wgid & 7, slot = wgid >> 3;
  const int bh = xcd + 8 * (slot >> 4);
  const int qt = 15 - (slot & 15);  // heavy tiles first within each bh
  const int b = bh >> 4, h = bh & 15;
  const int tid = threadIdx.x, wv = tid >> 6, lane = tid & 63;
  const int lr = lane & 15, lg = lane >> 4;
  const f16* Qb = qk16 + ((long)b * Sn + qt * 128) * LDQK + h * DH;
  const f16* Kb = qk16 + (long)b * Sn * LDQK + Dn + h * DH;
  const f16* Vb = vT + (long)h * DH * MROWS + (long)b * Sn;
  float* Wrow = wts + (long)bh * Sn * Sn + (long)qt * 128 * Sn;
  __shared__ __align__(16) f16 sK[2][128 * 128];  // ping-pong K tiles (Q boot in sK[0])

  // per-thread K-prefetch mapping: 8 chunks of 16B cover 128x128 f16
  const int krr = tid >> 4;          // 0..15
  const int kce = (tid & 15) * 8;    // f16 col
  const int kcb = kce * 2;           // byte col
  f16x8 kpf[8];

#define PRE_K(kt_)                                                              \
  {                                                                             \
    const long kbase = (long)(kt_)*128;                                         \
    _Pragma("unroll") for (int ch = 0; ch < 8; ++ch) kpf[ch] =                  \
        *(const f16x8*)(Kb + (kbase + ch * 16 + krr) * LDQK + kce);             \
  }
#define PUB_K(buf)                                                              \
  {                                                                             \
    _Pragma("unroll") for (int ch = 0; ch < 8; ++ch) {                          \
      const int r = ch * 16 + krr;                                              \
      *(f16x8*)((char*)(buf) + r * 256 + (kcb ^ ((r & 7) << 4))) = kpf[ch];     \
    }                                                                           \
  }
// PV accumulate over weight tile j: A-fragments from the fp32 weights (L1-hot),
// B-fragments from vT. 64 MFMA per call per wave.
#define PV_TILE(j)                                                              \
  {                                                                             \
    _Pragma("unroll") for (int kk = 0; kk < 4; ++kk) {                          \
      f16x8 af[2], bfr[8];                                                      \
      _Pragma("unroll") for (int m = 0; m < 2; ++m) {                           \
        const float* wp =                                                       \
            Wrow + (long)(wq0 + m * 16 + lr) * Sn + (j)*128 + kk * 32 + lg * 8; \
        float4 x0 = *(const float4*)wp;                                         \
        float4 x1 = *(const float4*)(wp + 4);                                   \
        f16x8 t;                                                                \
        t[0] = (f16)x0.x; t[1] = (f16)x0.y; t[2] = (f16)x0.z; t[3] = (f16)x0.w; \
        t[4] = (f16)x1.x; t[5] = (f16)x1.y; t[6] = (f16)x1.z; t[7] = (f16)x1.w; \
        af[m] = t;                                                              \
      }                                                                         \
      _Pragma("unroll") for (int n = 0; n < 8; ++n) bfr[n] =                    \
          *(const f16x8*)(Vb + (long)(n * 16 + lr) * MROWS + (j)*128 +          \
                          kk * 32 + lg * 8);                                    \
      _Pragma("unroll") for (int m = 0; m < 2; ++m)                             \
          _Pragma("unroll") for (int n = 0; n < 8; ++n) pacc[m][n] =            \
          MFMA(af[m], bfr[n], pacc[m][n]);                                      \
    }                                                                           \
  }

  // ---- prologue: Q through sK[0], K tile 0 into regs ----
  stage_tile128(Qb, LDQK, sK[0]);
  PRE_K(0);
  __syncthreads();
  const int wq0 = wv * 32;
  f16x8 qf[2][4];
#pragma unroll
  for (int m = 0; m < 2; ++m)
#pragma unroll
    for (int kk = 0; kk < 4; ++kk)
      qf[m][kk] = ldfrag128(sK[0], wq0 + m * 16 + lr, kk * 32 + lg * 8);
  __syncthreads();  // all waves done reading Q from sK[0]
  PUB_K(sK[0]);
  if (qt > 0) PRE_K(1);
  __syncthreads();
  int cur = 0;

  // ---- phase 1: causal row sums of exp2(s'); per-lane partials, reduce once ----
  float rs[2][4] = {};
  for (int kt = 0; kt <= qt; ++kt) {
    f32x4 acc[2][8] = {};
#pragma unroll
    for (int kk = 0; kk < 4; ++kk) {
      f16x8 bf[8];
#pragma unroll
      for (int n = 0; n < 8; ++n) bf[n] = ldfrag128(sK[cur], n * 16 + lr, kk * 32 + lg * 8);
#pragma unroll
      for (int m = 0; m < 2; ++m)
#pragma unroll
        for (int n = 0; n < 8; ++n) acc[m][n] = MFMA(qf[m][kk], bf[n], acc[m][n]);
    }
    // publish next tile into the other buffer (overlaps other waves' MFMA)
    if (kt + 1 <= qt) PUB_K(sK[cur ^ 1]);
    PRE_K(kt + 2 <= qt ? kt + 2 : 0);  // tail preloads tile 0 for phase 2
    const bool diag = (kt == qt);
#pragma unroll
    for (int m = 0; m < 2; ++m)
#pragma unroll
      for (int r = 0; r < 4; ++r) {
        const int row = wq0 + m * 16 + lg * 4 + r;
        float ts = 0.f;
#pragma unroll
        for (int n = 0; n < 8; ++n) {
          const bool ok = !diag || (n * 16 + lr) <= row;
          ts += ok ? __builtin_amdgcn_exp2f(acc[m][n][r]) : 0.f;
        }
        rs[m][r] += ts;  // per-lane partial; cross-lane reduce deferred
      }
    __syncthreads();
    cur ^= 1;
  }
  float ri[2][4];
#pragma unroll
  for (int m = 0; m < 2; ++m)
#pragma unroll
    for (int r = 0; r < 4; ++r) {
      float s = rs[m][r];
#pragma unroll
      for (int o = 1; o < 16; o <<= 1) s += __shfl_xor(s, o, 64);
      ri[m][r] = 1.f / s;
    }

  // ---- phase 2 prologue: kpf holds tile 0 ----
  PUB_K(sK[cur ^ 1]);
  if (qt > 0) PRE_K(1);
  __syncthreads();
  cur ^= 1;

  // ---- phase 2: QK -> normalize -> W store (plain) -> PV over PREVIOUS tile ----
  f32x4 pacc[2][8] = {};
  for (int kt = 0; kt <= qt; ++kt) {
    f32x4 sacc[2][8] = {};
#pragma unroll
    for (int kk = 0; kk < 4; ++kk) {
      f16x8 bf[8];
#pragma unroll
      for (int n = 0; n < 8; ++n) bf[n] = ldfrag128(sK[cur], n * 16 + lr, kk * 32 + lg * 8);
#pragma unroll
      for (int m = 0; m < 2; ++m)
#pragma unroll
        for (int n = 0; n < 8; ++n) sacc[m][n] = MFMA(qf[m][kk], bf[n], sacc[m][n]);
    }
    if (kt + 1 <= qt) PUB_K(sK[cur ^ 1]);
    if (kt + 2 <= qt) PRE_K(kt + 2);
    // normalize -> plain coalesced W stores (read back by PV next iteration)
    const bool diag = (kt == qt);
#pragma unroll
    for (int m = 0; m < 2; ++m)
#pragma unroll
      for (int n = 0; n < 8; ++n) {
        const int col = n * 16 + lr;
#pragma unroll
        for (int r = 0; r < 4; ++r) {
          const int row = wq0 + m * 16 + lg * 4 + r;
          float w = __builtin_amdgcn_exp2f(sacc[m][n][r]) * ri[m][r];
          if (diag && col > row) w = 0.f;
          Wrow[(long)row * Sn + kt * 128 + col] = w;
        }
      }
    // PV over the previous tile (its W stores drained by last __syncthreads)
    if (kt > 0) PV_TILE(kt - 1);
    __syncthreads();
    cur ^= 1;
  }
  // epilogue PV over the final tile (its stores drained by the last barrier)
  PV_TILE(qt);

  // ctx epilogue
#pragma unroll
  for (int m = 0; m < 2; ++m)
#pragma unroll
    for (int n = 0; n < 8; ++n) {
      const int d = n * 16 + lr;
#pragma unroll
      for (int r = 0; r < 4; ++r) {
        const int q = qt * 128 + wq0 + m * 16 + lg * 4 + r;
        ctx[(long)(b * Sn + q) * Dn + h * DH + d] = (f16)pacc[m][n][r];
      }
    }
#undef PRE_K
#undef PUB_K
#undef PV_TILE
}

extern "C" void kernel_launch(void* const* d_in, const int* in_sizes, int n_in,
                              void* d_out, int out_size, void* d_ws, size_t ws_size,
                              hipStream_t stream) {
  const float* hid = (const float*)d_in[0];
  const float* wq = (const float*)d_in[1];
  const float* wk = (const float*)d_in[2];
  const float* wv = (const float*)d_in[3];
  const float* wo = (const float*)d_in[4];
  const float* bo = (const float*)d_in[5];
  float* out = (float*)d_out;
  float* wts = out + (long)Bc * Sn * Dn;  // attn_weights region: [64][2048][2048] fp32

  char* ws = (char*)d_ws;
  const long MB = 1 << 20;
  f16* h16 = (f16*)(ws + 0 * MB);       // 32 MB
  f16* wqk16 = (f16*)(ws + 32 * MB);    // 16 MB ([wq; wk] rows)
  f16* wv16 = (f16*)(ws + 48 * MB);     // 8 MB
  f16* wo16 = (f16*)(ws + 56 * MB);     // 8 MB
  f16* qk16 = (f16*)(ws + 64 * MB);     // 64 MB  [8192 x 4096] (q | k)
  f16* vT = (f16*)(ws + 128 * MB);      // 32 MB
  f16* ctx = (f16*)(ws + 160 * MB);     // 32 MB

  // all converts, one launch
  k_cvt_all<<<dim3(4096, 8), 256, 0, stream>>>(
      hid, wq, wk, wv, wo, h16, wqk16, wv16, wo16);
  // qk-GEMM (q scaled by log2e) + vT-GEMM + upper-triangle zfill, one launch
  k_fused<<<4096, 256, 0, stream>>>(h16, wqk16, wv16, qk16, vT, wts);
  // fused attention: sum-only stats + recompute + lower-tri weight write + PV
  k_attn<<<1024, 256, 0, stream>>>(qk16, vT, wts, ctx);
  // out = ctx @ wo^T + bo
  k_gemm_wo<<<dim3(16, 64), 256, 0, stream>>>(ctx, wo16, out, bo);
}

// Round 20
// 1075.143 us; speedup vs baseline: 1.0040x; 1.0040x over previous
//
#include <hip/hip_runtime.h>

#define DEVFN static __device__ __forceinline__

typedef _Float16 f16;
typedef f16 f16x8 __attribute__((ext_vector_type(8)));
typedef f16 f16x4 __attribute__((ext_vector_type(4)));
typedef float f32x4 __attribute__((ext_vector_type(4)));
typedef short short8 __attribute__((ext_vector_type(8)));

constexpr int Bc = 4, Hn = 16, Sn = 2048, DH = 128, Dn = 2048;
constexpr long MROWS = (long)Bc * Sn;  // 8192
constexpr long LDQK = 2 * Dn;          // 4096 (q|k concatenated)

// ---------- MFMA wrapper: dual-signature dispatch (half8 preferred, short8 fallback) ----------
template <typename T, typename C>
DEVFN auto mfma_impl(T a, T b, C c, int)
    -> decltype(__builtin_amdgcn_mfma_f32_16x16x32_f16(a, b, c, 0, 0, 0)) {
  return __builtin_amdgcn_mfma_f32_16x16x32_f16(a, b, c, 0, 0, 0);
}
template <typename T, typename C>
DEVFN C mfma_impl(T a, T b, C c, long) {
  return __builtin_amdgcn_mfma_f32_16x16x32_f16(
      __builtin_bit_cast(short8, a), __builtin_bit_cast(short8, b), c, 0, 0, 0);
}
DEVFN f32x4 MFMA(f16x8 a, f16x8 b, f32x4 c) { return mfma_impl(a, b, c, 0); }

// ---------- non-temporal store helpers (write-once streams; keep L2 for K/V) ----------
DEVFN void nt_store(float* p, float v) { __builtin_nontemporal_store(v, p); }
DEVFN void nt_store4(float* p, f32x4 v) {
  __builtin_nontemporal_store(v, (f32x4*)p);
}

// ---------- async global->LDS 16B ----------
DEVFN void gld_lds16(const f16* g, f16* s) {
  __builtin_amdgcn_global_load_lds(
      (const __attribute__((address_space(1))) unsigned int*)g,
      (__attribute__((address_space(3))) unsigned int*)s, 16, 0, 0);
}

// Stage a 128x64 f16 tile (row stride ld elems) into LDS, linear dest,
// source pre-swizzled so reads with byte^((row&7)<<4) are conflict-free.
DEVFN void stage_tile(const f16* __restrict__ g, long ld, f16* __restrict__ s) {
  const int t = threadIdx.x;
  const int rr = t >> 3;
  const int cb = (t & 7) * 16;  // byte offset within 128B row
#pragma unroll
  for (int ch = 0; ch < 4; ++ch) {
    const int r = ch * 32 + rr;
    const int scb = cb ^ ((r & 7) << 4);
    gld_lds16(g + (long)r * ld + (scb >> 1), s + r * 64 + (cb >> 1));
  }
}

// Stage a 128x128 f16 tile (row stride ld elems), same swizzle, 256B rows, 256 threads.
DEVFN void stage_tile128(const f16* __restrict__ g, long ld, f16* __restrict__ s) {
  const int t = threadIdx.x;
  const int rr = t >> 4;         // 0..15
  const int cb = (t & 15) * 16;  // byte col 0..255
#pragma unroll
  for (int ch = 0; ch < 8; ++ch) {
    const int r = ch * 16 + rr;
    const int scb = cb ^ ((r & 7) << 4);
    gld_lds16(g + (long)r * ld + (scb >> 1), s + r * 128 + (cb >> 1));
  }
}

// Swizzled fragment read: 8 contiguous f16 at (tile-local row, k element), 64-col tile
DEVFN f16x8 ldfrag(const f16* s, int row, int kelem) {
  const int cb = (kelem * 2) ^ ((row & 7) << 4);
  return *(const f16x8*)(s + row * 64 + (cb >> 1));
}

// 128-col f16 tile variant (row stride 256 B)
DEVFN f16x8 ldfrag128(const f16* s, int row, int kelem) {
  const int cb = (kelem * 2) ^ ((row & 7) << 4);
  return *(const f16x8*)((const char*)s + row * 256 + cb);
}

// ---------- all five fp32->f16 converts in ONE launch ----------
// grid (4096, 8): y<4 -> hid quarter y; y=4..7 -> wq/wk/wv/wo
__global__ __launch_bounds__(256) void k_cvt_all(
    const float* __restrict__ hid, const float* __restrict__ wq,
    const float* __restrict__ wk, const float* __restrict__ wv,
    const float* __restrict__ wo, f16* __restrict__ h16,
    f16* __restrict__ wqk16, f16* __restrict__ wv16, f16* __restrict__ wo16) {
  const int y = blockIdx.y;
  const long nW = (long)Dn * Dn;
  const float* x;
  f16* out;
  if (y < 4) {
    x = hid + (long)y * nW;
    out = h16 + (long)y * nW;
  } else if (y == 4) {
    x = wq; out = wqk16;
  } else if (y == 5) {
    x = wk; out = wqk16 + nW;
  } else if (y == 6) {
    x = wv; out = wv16;
  } else {
    x = wo; out = wo16;
  }
  const long i = ((long)blockIdx.x * 256 + threadIdx.x) * 4;
  float4 v = *(const float4*)(x + i);
  f16x4 h;
  h[0] = (f16)v.x; h[1] = (f16)v.y; h[2] = (f16)v.z; h[3] = (f16)v.w;
  *(f16x4*)(out + i) = h;
}

// ---------- GEMM body (C = oscale * A@B^T, f16 out), 2-phase double-buffered LDS ----------
DEVFN void gemm_body(const f16* __restrict__ A, long ldA,
                     const f16* __restrict__ B, long ldB, int K,
                     f16* __restrict__ oh, long ldC, int nt, int mt,
                     float oscale, f16* sA, f16* sB) {
  const int tid = threadIdx.x, w = tid >> 6, lane = tid & 63;
  const int wm = (w >> 1) * 64, wn = (w & 1) * 64;
  const int lr = lane & 15, lg = lane >> 4;
  f32x4 acc[4][4] = {};
  const f16* Ab = A + (long)mt * 128 * ldA;
  const f16* Bb = B + (long)nt * 128 * ldB;

  stage_tile(Ab, ldA, sA);
  stage_tile(Bb, ldB, sB);
  __syncthreads();

  int cur = 0;
  for (int kt = 0; kt < K; kt += 64) {
    if (kt + 64 < K) {
      stage_tile(Ab + kt + 64, ldA, sA + (cur ^ 1) * (128 * 64));
      stage_tile(Bb + kt + 64, ldB, sB + (cur ^ 1) * (128 * 64));
    }
    const f16* cA = sA + cur * (128 * 64);
    const f16* cB = sB + cur * (128 * 64);
#pragma unroll
    for (int kk = 0; kk < 64; kk += 32) {
      f16x8 ahf[4], bhf[4];
#pragma unroll
      for (int m = 0; m < 4; ++m) ahf[m] = ldfrag(cA, wm + m * 16 + lr, kk + lg * 8);
#pragma unroll
      for (int n = 0; n < 4; ++n) bhf[n] = ldfrag(cB, wn + n * 16 + lr, kk + lg * 8);
#pragma unroll
      for (int m = 0; m < 4; ++m)
#pragma unroll
        for (int n = 0; n < 4; ++n) acc[m][n] = MFMA(ahf[m], bhf[n], acc[m][n]);
    }
    __syncthreads();
    cur ^= 1;
  }

#pragma unroll
  for (int m = 0; m < 4; ++m)
#pragma unroll
    for (int n = 0; n < 4; ++n) {
      const int col = nt * 128 + wn + n * 16 + lr;
#pragma unroll
      for (int r = 0; r < 4; ++r) {
        const long row = (long)mt * 128 + wm + m * 16 + lg * 4 + r;
        oh[row * ldC + col] = (f16)(acc[m][n][r] * oscale);
      }
    }
}

// ---------- fused: qk-GEMM (2048 blk) + vT-GEMM (1024 blk) + zfill (1024 blk) ----------
// q columns pre-scaled by log2(e) so k_attn can use raw v_exp (exp2) directly.
__global__ __launch_bounds__(256) void k_fused(
    const f16* __restrict__ h16, const f16* __restrict__ wqk16,
    const f16* __restrict__ wv16, f16* __restrict__ qk16, f16* __restrict__ vT,
    float* __restrict__ wts) {
  __shared__ __align__(16) f16 sA[2 * 128 * 64];
  __shared__ __align__(16) f16 sB[2 * 128 * 64];
  const int bid = blockIdx.x;
  if ((bid & 3) == 3) {
    // ---- zfill role: zero strictly-upper-triangular weight tiles ----
    const int zid = bid >> 2;               // 0..1023
    const int bh = zid & 63, qt = zid >> 6; // 64 x 16
    const int ncols = Sn - (qt + 1) * 128;
    if (ncols <= 0) return;
    float* base = wts + (long)bh * Sn * Sn + (long)qt * 128 * Sn + (qt + 1) * 128;
    const int tid = threadIdx.x;
    const f32x4 z = {0.f, 0.f, 0.f, 0.f};
    for (int r = 0; r < 128; ++r) {
      float* rowp = base + (long)r * Sn;
      for (int c = tid * 4; c < ncols; c += 1024) nt_store4(rowp + c, z);
    }
    return;
  }
  const int gid = 3 * (bid >> 2) + (bid & 3);  // 0..3071
  if (gid < 2048) {
    // ---- qk GEMM: [8192 x 4096] = h16 @ wqk16^T ----
    const int cpx = 2048 >> 3;
    const int swz = (gid & 7) * cpx + (gid >> 3);
    const int nt = swz & 31, mt = swz >> 5;  // 32 x 64
    const float qsc = (nt < 16) ? 1.44269504f : 1.0f;  // log2(e) on q columns
    gemm_body(h16, Dn, wqk16, Dn, Dn, qk16, LDQK, nt, mt, qsc, sA, sB);
  } else {
    // ---- vT GEMM: [2048 x 8192] = wv16 @ h16^T ----
    const int sb = gid - 2048;
    const int cpx = 1024 >> 3;
    const int swz = (sb & 7) * cpx + (sb >> 3);
    const int nt = swz & 63, mt = swz >> 6;  // 64 x 16
    gemm_body(wv16, Dn, h16, Dn, Dn, vT, MROWS, nt, mt, 1.0f, sA, sB);
  }
}

// ---------- WO GEMM: out = ctx @ wo^T + bo (fp32 + bias, NT stores) ----------
__global__ __launch_bounds__(256) void k_gemm_wo(
    const f16* __restrict__ A, const f16* __restrict__ B,
    float* __restrict__ of, const float* __restrict__ bias) {
  const int nwgx = gridDim.x;
  const int nwg = nwgx * gridDim.y;
  const int bid = blockIdx.y * nwgx + blockIdx.x;
  const int cpx = nwg >> 3;
  const int swz = (bid & 7) * cpx + (bid >> 3);
  const int nt = swz % nwgx, mt = swz / nwgx;
  __shared__ __align__(16) f16 sA[2][128 * 64];
  __shared__ __align__(16) f16 sB[2][128 * 64];
  const int tid = threadIdx.x, w = tid >> 6, lane = tid & 63;
  const int wm = (w >> 1) * 64, wn = (w & 1) * 64;
  const int lr = lane & 15, lg = lane >> 4;
  f32x4 acc[4][4] = {};
  const f16* Ab = A + (long)mt * 128 * Dn;
  const f16* Bb = B + (long)nt * 128 * Dn;

  stage_tile(Ab, Dn, sA[0]);
  stage_tile(Bb, Dn, sB[0]);
  __syncthreads();

  int cur = 0;
  for (int kt = 0; kt < Dn; kt += 64) {
    if (kt + 64 < Dn) {
      stage_tile(Ab + kt + 64, Dn, sA[cur ^ 1]);
      stage_tile(Bb + kt + 64, Dn, sB[cur ^ 1]);
    }
#pragma unroll
    for (int kk = 0; kk < 64; kk += 32) {
      f16x8 ahf[4], bhf[4];
#pragma unroll
      for (int m = 0; m < 4; ++m) ahf[m] = ldfrag(sA[cur], wm + m * 16 + lr, kk + lg * 8);
#pragma unroll
      for (int n = 0; n < 4; ++n) bhf[n] = ldfrag(sB[cur], wn + n * 16 + lr, kk + lg * 8);
#pragma unroll
      for (int m = 0; m < 4; ++m)
#pragma unroll
        for (int n = 0; n < 4; ++n) acc[m][n] = MFMA(ahf[m], bhf[n], acc[m][n]);
    }
    __syncthreads();
    cur ^= 1;
  }

#pragma unroll
  for (int m = 0; m < 4; ++m)
#pragma unroll
    for (int n = 0; n < 4; ++n) {
      const int col = nt * 128 + wn + n * 16 + lr;
#pragma unroll
      for (int r = 0; r < 4; ++r) {
        const long row = (long)mt * 128 + wm + m * 16 + lg * 4 + r;
        nt_store(of + row * Dn + col, acc[m][n][r] + bias[col]);
      }
    }
}

// ---------- fused attention, sum-only softmax (exp2, q pre-scaled) ----------
// Ping-pong K buffer, ONE barrier per tile. No LDS P-stash: W is written with
// plain (cacheable) stores and PV reads its A-fragments back from the weights
// one tile behind (wave-own rows; the intervening __syncthreads drains vmcnt,
// so the stores have landed and the lines are L1/L2-hot).
__global__ __launch_bounds__(256) void k_attn(const f16* __restrict__ qk16,
                                              const f16* __restrict__ vT,
                                              float* __restrict__ wts,
                                              f16* __restrict__ ctx) {
  const int wgid = blockIdx.x;
  const int xcd = wgid & 7, slot = wgid >> 3;
  const int bh = xcd + 8 * (slot >> 4);
  const int qt = 15 - (slot & 15);  // heavy tiles first within each bh
  const int b = bh >> 4, h = bh & 15;
  const int tid = threadIdx.x, wv = tid >> 6, lane = tid & 63;
  const int lr = lane & 15, lg = lane >> 4;
  const f16* Qb = qk16 + ((long)b * Sn + qt * 128) * LDQK + h * DH;
  const f16* Kb = qk16 + (long)b * Sn * LDQK + Dn + h * DH;
  const f16* Vb = vT + (long)h * DH * MROWS + (long)b * Sn;
  float* Wrow = wts + (long)bh * Sn * Sn + (long)qt * 128 * Sn;
  __shared__ __align__(16) f16 sK[2][128 * 128];  // ping-pong K tiles (Q boot in sK[0])

  // per-thread K-prefetch mapping: 8 chunks of 16B cover 128x128 f16
  const int krr = tid >> 4;          // 0..15
  const int kce = (tid & 15) * 8;    // f16 col
  const int kcb = kce * 2;           // byte col
  f16x8 kpf[8];

#define PRE_K(kt_)                                                              \
  {                                                                             \
    const long kbase = (long)(kt_)*128;                                         \
    _Pragma("unroll") for (int ch = 0; ch < 8; ++ch) kpf[ch] =                  \
        *(const f16x8*)(Kb + (kbase + ch * 16 + krr) * LDQK + kce);             \
  }
#define PUB_K(buf)                                                              \
  {                                                                             \
    _Pragma("unroll") for (int ch = 0; ch < 8; ++ch) {                          \
      const int r = ch * 16 + krr;                                              \
      *(f16x8*)((char*)(buf) + r * 256 + (kcb ^ ((r & 7) << 4))) = kpf[ch];     \
    }                                                                           \
  }
// PV accumulate over weight tile j: A-fragments from the fp32 weights (L1-hot),
// B-fragments from vT. 64 MFMA per call per wave.
#define PV_TILE(j)                                                              \
  {                                                                             \
    _Pragma("unroll") for (int kk = 0; kk < 4; ++kk) {                          \
      f16x8 af[2], bfr[8];                                                      \
      _Pragma("unroll") for (int m = 0; m < 2; ++m) {                           \
        const float* wp =                                                       \
            Wrow + (long)(wq0 + m * 16 + lr) * Sn + (j)*128 + kk * 32 + lg * 8; \
        float4 x0 = *(const float4*)wp;                                         \
        float4 x1 = *(const float4*)(wp + 4);                                   \
        f16x8 t;                                                                \
        t[0] = (f16)x0.x; t[1] = (f16)x0.y; t[2] = (f16)x0.z; t[3] = (f16)x0.w; \
        t[4] = (f16)x1.x; t[5] = (f16)x1.y; t[6] = (f16)x1.z; t[7] = (f16)x1.w; \
        af[m] = t;                                                              \
      }                                                                         \
      _Pragma("unroll") for (int n = 0; n < 8; ++n) bfr[n] =                    \
          *(const f16x8*)(Vb + (long)(n * 16 + lr) * MROWS + (j)*128 +          \
                          kk * 32 + lg * 8);                                    \
      _Pragma("unroll") for (int m = 0; m < 2; ++m)                             \
          _Pragma("unroll") for (int n = 0; n < 8; ++n) pacc[m][n] =            \
          MFMA(af[m], bfr[n], pacc[m][n]);                                      \
    }                                                                           \
  }

  // ---- prologue: Q through sK[0], K tile 0 into regs ----
  stage_tile128(Qb, LDQK, sK[0]);
  PRE_K(0);
  __syncthreads();
  const int wq0 = wv * 32;
  f16x8 qf[2][4];
#pragma unroll
  for (int m = 0; m < 2; ++m)
#pragma unroll
    for (int kk = 0; kk < 4; ++kk)
      qf[m][kk] = ldfrag128(sK[0], wq0 + m * 16 + lr, kk * 32 + lg * 8);
  __syncthreads();  // all waves done reading Q from sK[0]
  PUB_K(sK[0]);
  if (qt > 0) PRE_K(1);
  __syncthreads();
  int cur = 0;

  // ---- phase 1: causal row sums of exp2(s'); per-lane partials, reduce once ----
  float rs[2][4] = {};
  for (int kt = 0; kt <= qt; ++kt) {
    f32x4 acc[2][8] = {};
#pragma unroll
    for (int kk = 0; kk < 4; ++kk) {
      f16x8 bf[8];
#pragma unroll
      for (int n = 0; n < 8; ++n) bf[n] = ldfrag128(sK[cur], n * 16 + lr, kk * 32 + lg * 8);
#pragma unroll
      for (int m = 0; m < 2; ++m)
#pragma unroll
        for (int n = 0; n < 8; ++n) acc[m][n] = MFMA(qf[m][kk], bf[n], acc[m][n]);
    }
    // publish next tile into the other buffer (overlaps other waves' MFMA)
    if (kt + 1 <= qt) PUB_K(sK[cur ^ 1]);
    PRE_K(kt + 2 <= qt ? kt + 2 : 0);  // tail preloads tile 0 for phase 2
    const bool diag = (kt == qt);
#pragma unroll
    for (int m = 0; m < 2; ++m)
#pragma unroll
      for (int r = 0; r < 4; ++r) {
        const int row = wq0 + m * 16 + lg * 4 + r;
        float ts = 0.f;
#pragma unroll
        for (int n = 0; n < 8; ++n) {
          const bool ok = !diag || (n * 16 + lr) <= row;
          ts += ok ? __builtin_amdgcn_exp2f(acc[m][n][r]) : 0.f;
        }
        rs[m][r] += ts;  // per-lane partial; cross-lane reduce deferred
      }
    __syncthreads();
    cur ^= 1;
  }
  float ri[2][4];
#pragma unroll
  for (int m = 0; m < 2; ++m)
#pragma unroll
    for (int r = 0; r < 4; ++r) {
      float s = rs[m][r];
#pragma unroll
      for (int o = 1; o < 16; o <<= 1) s += __shfl_xor(s, o, 64);
      ri[m][r] = 1.f / s;
    }

  // ---- phase 2 prologue: kpf holds tile 0 ----
  PUB_K(sK[cur ^ 1]);
  if (qt > 0) PRE_K(1);
  __syncthreads();
  cur ^= 1;

  // ---- phase 2: QK -> normalize -> W store (plain) -> PV over PREVIOUS tile ----
  f32x4 pacc[2][8] = {};
  for (int kt = 0; kt <= qt; ++kt) {
    f32x4 sacc[2][8] = {};
#pragma unroll
    for (int kk = 0; kk < 4; ++kk) {
      f16x8 bf[8];
#pragma unroll
      for (int n = 0; n < 8; ++n) bf[n] = ldfrag128(sK[cur], n * 16 + lr, kk * 32 + lg * 8);
#pragma unroll
      for (int m = 0; m < 2; ++m)
#pragma unroll
        for (int n = 0; n < 8; ++n) sacc[m][n] = MFMA(qf[m][kk], bf[n], sacc[m][n]);
    }
    if (kt + 1 <= qt) PUB_K(sK[cur ^ 1]);
    if (kt + 2 <= qt) PRE_K(kt + 2);
    // normalize -> plain coalesced W stores (read back by PV next iteration)
    const bool diag = (kt == qt);
#pragma unroll
    for (int m = 0; m < 2; ++m)
#pragma unroll
      for (int n = 0; n < 8; ++n) {
        const int col = n * 16 + lr;
#pragma unroll
        for (int r = 0; r < 4; ++r) {
          const int row = wq0 + m * 16 + lg * 4 + r;
          float w = __builtin_amdgcn_exp2f(sacc[m][n][r]) * ri[m][r];
          if (diag && col > row) w = 0.f;
          Wrow[(long)row * Sn + kt * 128 + col] = w;
        }
      }
    // PV over the previous tile (its W stores drained by last __syncthreads)
    if (kt > 0) PV_TILE(kt - 1);
    __syncthreads();
    cur ^= 1;
  }
  // epilogue PV over the final tile (its stores drained by the last barrier)
  PV_TILE(qt);

  // ctx epilogue
#pragma unroll
  for (int m = 0; m < 2; ++m)
#pragma unroll
    for (int n = 0; n < 8; ++n) {
      const int d = n * 16 + lr;
#pragma unroll
      for (int r = 0; r < 4; ++r) {
        const int q = qt * 128 + wq0 + m * 16 + lg * 4 + r;
        ctx[(long)(b * Sn + q) * Dn + h * DH + d] = (f16)pacc[m][n][r];
      }
    }
#undef PRE_K
#undef PUB_K
#undef PV_TILE
}

extern "C" void kernel_launch(void* const* d_in, const int* in_sizes, int n_in,
                              void* d_out, int out_size, void* d_ws, size_t ws_size,
                              hipStream_t stream) {
  const float* hid = (const float*)d_in[0];
  const float* wq = (const float*)d_in[1];
  const float* wk = (const float*)d_in[2];
  const float* wv = (const float*)d_in[3];
  const float* wo = (const float*)d_in[4];
  const float* bo = (const float*)d_in[5];
  float* out = (float*)d_out;
  float* wts = out + (long)Bc * Sn * Dn;  // attn_weights region: [64][2048][2048] fp32

  char* ws = (char*)d_ws;
  const long MB = 1 << 20;
  f16* h16 = (f16*)(ws + 0 * MB);       // 32 MB
  f16* wqk16 = (f16*)(ws + 32 * MB);    // 16 MB ([wq; wk] rows)
  f16* wv16 = (f16*)(ws + 48 * MB);     // 8 MB
  f16* wo16 = (f16*)(ws + 56 * MB);     // 8 MB
  f16* qk16 = (f16*)(ws + 64 * MB);     // 64 MB  [8192 x 4096] (q | k)
  f16* vT = (f16*)(ws + 128 * MB);      // 32 MB
  f16* ctx = (f16*)(ws + 160 * MB);     // 32 MB

  // all converts, one launch
  k_cvt_all<<<dim3(4096, 8), 256, 0, stream>>>(
      hid, wq, wk, wv, wo, h16, wqk16, wv16, wo16);
  // qk-GEMM (q scaled by log2e) + vT-GEMM + upper-triangle zfill, one launch
  k_fused<<<4096, 256, 0, stream>>>(h16, wqk16, wv16, qk16, vT, wts);
  // fused attention: sum-only stats + recompute + lower-tri weight write + PV
  k_attn<<<1024, 256, 0, stream>>>(qk16, vT, wts, ctx);
  // out = ctx @ wo^T + bo
  k_gemm_wo<<<dim3(16, 64), 256, 0, stream>>>(ctx, wo16, out, bo);
}

// Round 21
// 756.634 us; speedup vs baseline: 1.4266x; 1.4210x over previous
//
#include <hip/hip_runtime.h>

#define DEVFN static __device__ __forceinline__

typedef _Float16 f16;
typedef f16 f16x8 __attribute__((ext_vector_type(8)));
typedef f16 f16x4 __attribute__((ext_vector_type(4)));
typedef float f32x4 __attribute__((ext_vector_type(4)));
typedef short short8 __attribute__((ext_vector_type(8)));

constexpr int Bc = 4, Hn = 16, Sn = 2048, DH = 128, Dn = 2048;
constexpr long MROWS = (long)Bc * Sn;  // 8192
constexpr long LDQK = 2 * Dn;          // 4096 (q|k concatenated)

// ---------- MFMA wrapper: dual-signature dispatch (half8 preferred, short8 fallback) ----------
template <typename T, typename C>
DEVFN auto mfma_impl(T a, T b, C c, int)
    -> decltype(__builtin_amdgcn_mfma_f32_16x16x32_f16(a, b, c, 0, 0, 0)) {
  return __builtin_amdgcn_mfma_f32_16x16x32_f16(a, b, c, 0, 0, 0);
}
template <typename T, typename C>
DEVFN C mfma_impl(T a, T b, C c, long) {
  return __builtin_amdgcn_mfma_f32_16x16x32_f16(
      __builtin_bit_cast(short8, a), __builtin_bit_cast(short8, b), c, 0, 0, 0);
}
DEVFN f32x4 MFMA(f16x8 a, f16x8 b, f32x4 c) { return mfma_impl(a, b, c, 0); }

// ---------- non-temporal store helpers (write-once streams; keep L2 for K/V) ----------
DEVFN void nt_store(float* p, float v) { __builtin_nontemporal_store(v, p); }
DEVFN void nt_store4(float* p, f32x4 v) {
  __builtin_nontemporal_store(v, (f32x4*)p);
}

// ---------- async global->LDS 16B ----------
DEVFN void gld_lds16(const f16* g, f16* s) {
  __builtin_amdgcn_global_load_lds(
      (const __attribute__((address_space(1))) unsigned int*)g,
      (__attribute__((address_space(3))) unsigned int*)s, 16, 0, 0);
}

// Stage a 128x64 f16 tile (row stride ld elems) into LDS, linear dest,
// source pre-swizzled so reads with byte^((row&7)<<4) are conflict-free.
DEVFN void stage_tile(const f16* __restrict__ g, long ld, f16* __restrict__ s) {
  const int t = threadIdx.x;
  const int rr = t >> 3;
  const int cb = (t & 7) * 16;  // byte offset within 128B row
#pragma unroll
  for (int ch = 0; ch < 4; ++ch) {
    const int r = ch * 32 + rr;
    const int scb = cb ^ ((r & 7) << 4);
    gld_lds16(g + (long)r * ld + (scb >> 1), s + r * 64 + (cb >> 1));
  }
}

// Stage a 128x128 f16 tile (row stride ld elems), same swizzle, 256B rows, 256 threads.
DEVFN void stage_tile128(const f16* __restrict__ g, long ld, f16* __restrict__ s) {
  const int t = threadIdx.x;
  const int rr = t >> 4;         // 0..15
  const int cb = (t & 15) * 16;  // byte col 0..255
#pragma unroll
  for (int ch = 0; ch < 8; ++ch) {
    const int r = ch * 16 + rr;
    const int scb = cb ^ ((r & 7) << 4);
    gld_lds16(g + (long)r * ld + (scb >> 1), s + r * 128 + (cb >> 1));
  }
}

// Swizzled fragment read: 8 contiguous f16 at (tile-local row, k element), 64-col tile
DEVFN f16x8 ldfrag(const f16* s, int row, int kelem) {
  const int cb = (kelem * 2) ^ ((row & 7) << 4);
  return *(const f16x8*)(s + row * 64 + (cb >> 1));
}

// 128-col f16 tile variant (row stride 256 B)
DEVFN f16x8 ldfrag128(const f16* s, int row, int kelem) {
  const int cb = (kelem * 2) ^ ((row & 7) << 4);
  return *(const f16x8*)((const char*)s + row * 256 + cb);
}

// 64-col f16 tile variant (row stride 128 B)
DEVFN f16x8 ldfrag64(const f16* s, int row, int kelem) {
  const int cb = (kelem * 2) ^ ((row & 7) << 4);
  return *(const f16x8*)((const char*)s + row * 128 + cb);
}

// ---------- all five fp32->f16 converts in ONE launch ----------
// grid (4096, 8): y<4 -> hid quarter y; y=4..7 -> wq/wk/wv/wo
__global__ __launch_bounds__(256) void k_cvt_all(
    const float* __restrict__ hid, const float* __restrict__ wq,
    const float* __restrict__ wk, const float* __restrict__ wv,
    const float* __restrict__ wo, f16* __restrict__ h16,
    f16* __restrict__ wqk16, f16* __restrict__ wv16, f16* __restrict__ wo16) {
  const int y = blockIdx.y;
  const long nW = (long)Dn * Dn;
  const float* x;
  f16* out;
  if (y < 4) {
    x = hid + (long)y * nW;
    out = h16 + (long)y * nW;
  } else if (y == 4) {
    x = wq; out = wqk16;
  } else if (y == 5) {
    x = wk; out = wqk16 + nW;
  } else if (y == 6) {
    x = wv; out = wv16;
  } else {
    x = wo; out = wo16;
  }
  const long i = ((long)blockIdx.x * 256 + threadIdx.x) * 4;
  float4 v = *(const float4*)(x + i);
  f16x4 h;
  h[0] = (f16)v.x; h[1] = (f16)v.y; h[2] = (f16)v.z; h[3] = (f16)v.w;
  *(f16x4*)(out + i) = h;
}

// ---------- GEMM body (C = oscale * A@B^T, f16 out), 2-phase double-buffered LDS ----------
DEVFN void gemm_body(const f16* __restrict__ A, long ldA,
                     const f16* __restrict__ B, long ldB, int K,
                     f16* __restrict__ oh, long ldC, int nt, int mt,
                     float oscale, f16* sA, f16* sB) {
  const int tid = threadIdx.x, w = tid >> 6, lane = tid & 63;
  const int wm = (w >> 1) * 64, wn = (w & 1) * 64;
  const int lr = lane & 15, lg = lane >> 4;
  f32x4 acc[4][4] = {};
  const f16* Ab = A + (long)mt * 128 * ldA;
  const f16* Bb = B + (long)nt * 128 * ldB;

  stage_tile(Ab, ldA, sA);
  stage_tile(Bb, ldB, sB);
  __syncthreads();

  int cur = 0;
  for (int kt = 0; kt < K; kt += 64) {
    if (kt + 64 < K) {
      stage_tile(Ab + kt + 64, ldA, sA + (cur ^ 1) * (128 * 64));
      stage_tile(Bb + kt + 64, ldB, sB + (cur ^ 1) * (128 * 64));
    }
    const f16* cA = sA + cur * (128 * 64);
    const f16* cB = sB + cur * (128 * 64);
#pragma unroll
    for (int kk = 0; kk < 64; kk += 32) {
      f16x8 ahf[4], bhf[4];
#pragma unroll
      for (int m = 0; m < 4; ++m) ahf[m] = ldfrag(cA, wm + m * 16 + lr, kk + lg * 8);
#pragma unroll
      for (int n = 0; n < 4; ++n) bhf[n] = ldfrag(cB, wn + n * 16 + lr, kk + lg * 8);
#pragma unroll
      for (int m = 0; m < 4; ++m)
#pragma unroll
        for (int n = 0; n < 4; ++n) acc[m][n] = MFMA(ahf[m], bhf[n], acc[m][n]);
    }
    __syncthreads();
    cur ^= 1;
  }

#pragma unroll
  for (int m = 0; m < 4; ++m)
#pragma unroll
    for (int n = 0; n < 4; ++n) {
      const int col = nt * 128 + wn + n * 16 + lr;
#pragma unroll
      for (int r = 0; r < 4; ++r) {
        const long row = (long)mt * 128 + wm + m * 16 + lg * 4 + r;
        oh[row * ldC + col] = (f16)(acc[m][n][r] * oscale);
      }
    }
}

// ---------- fused: qk-GEMM (2048 blk) + vT-GEMM (1024 blk), pure GEMM ----------
// q columns pre-scaled by log2(e) so k_attn can use raw v_exp (exp2) directly.
// zfill moved into k_attn (upper-tri rows are owned by the matching attn block).
__global__ __launch_bounds__(256) void k_fused(
    const f16* __restrict__ h16, const f16* __restrict__ wqk16,
    const f16* __restrict__ wv16, f16* __restrict__ qk16, f16* __restrict__ vT) {
  __shared__ __align__(16) f16 sA[2 * 128 * 64];
  __shared__ __align__(16) f16 sB[2 * 128 * 64];
  const int bid = blockIdx.x;
  if (bid < 2048) {
    // ---- qk GEMM: [8192 x 4096] = h16 @ wqk16^T ----
    const int cpx = 2048 >> 3;
    const int swz = (bid & 7) * cpx + (bid >> 3);
    const int nt = swz & 31, mt = swz >> 5;  // 32 x 64
    const float qsc = (nt < 16) ? 1.44269504f : 1.0f;  // log2(e) on q columns
    gemm_body(h16, Dn, wqk16, Dn, Dn, qk16, LDQK, nt, mt, qsc, sA, sB);
  } else {
    // ---- vT GEMM: [2048 x 8192] = wv16 @ h16^T ----
    const int sb = bid - 2048;
    const int cpx = 1024 >> 3;
    const int swz = (sb & 7) * cpx + (sb >> 3);
    const int nt = swz & 63, mt = swz >> 6;  // 64 x 16
    gemm_body(wv16, Dn, h16, Dn, Dn, vT, MROWS, nt, mt, 1.0f, sA, sB);
  }
}

// ---------- WO GEMM: out = ctx @ wo^T + bo (fp32 + bias, NT stores) ----------
__global__ __launch_bounds__(256) void k_gemm_wo(
    const f16* __restrict__ A, const f16* __restrict__ B,
    float* __restrict__ of, const float* __restrict__ bias) {
  const int nwgx = gridDim.x;
  const int nwg = nwgx * gridDim.y;
  const int bid = blockIdx.y * nwgx + blockIdx.x;
  const int cpx = nwg >> 3;
  const int swz = (bid & 7) * cpx + (bid >> 3);
  const int nt = swz % nwgx, mt = swz / nwgx;
  __shared__ __align__(16) f16 sA[2][128 * 64];
  __shared__ __align__(16) f16 sB[2][128 * 64];
  const int tid = threadIdx.x, w = tid >> 6, lane = tid & 63;
  const int wm = (w >> 1) * 64, wn = (w & 1) * 64;
  const int lr = lane & 15, lg = lane >> 4;
  f32x4 acc[4][4] = {};
  const f16* Ab = A + (long)mt * 128 * Dn;
  const f16* Bb = B + (long)nt * 128 * Dn;

  stage_tile(Ab, Dn, sA[0]);
  stage_tile(Bb, Dn, sB[0]);
  __syncthreads();

  int cur = 0;
  for (int kt = 0; kt < Dn; kt += 64) {
    if (kt + 64 < Dn) {
      stage_tile(Ab + kt + 64, Dn, sA[cur ^ 1]);
      stage_tile(Bb + kt + 64, Dn, sB[cur ^ 1]);
    }
#pragma unroll
    for (int kk = 0; kk < 64; kk += 32) {
      f16x8 ahf[4], bhf[4];
#pragma unroll
      for (int m = 0; m < 4; ++m) ahf[m] = ldfrag(sA[cur], wm + m * 16 + lr, kk + lg * 8);
#pragma unroll
      for (int n = 0; n < 4; ++n) bhf[n] = ldfrag(sB[cur], wn + n * 16 + lr, kk + lg * 8);
#pragma unroll
      for (int m = 0; m < 4; ++m)
#pragma unroll
        for (int n = 0; n < 4; ++n) acc[m][n] = MFMA(ahf[m], bhf[n], acc[m][n]);
    }
    __syncthreads();
    cur ^= 1;
  }

#pragma unroll
  for (int m = 0; m < 4; ++m)
#pragma unroll
    for (int n = 0; n < 4; ++n) {
      const int col = nt * 128 + wn + n * 16 + lr;
#pragma unroll
      for (int r = 0; r < 4; ++r) {
        const long row = (long)mt * 128 + wm + m * 16 + lg * 4 + r;
        nt_store(of + row * Dn + col, acc[m][n][r] + bias[col]);
      }
    }
}

// ---------- fused attention (round-18 body) + per-block upper-tri zeroing ----------
// Ping-pong K buffer, ONE barrier per tile. Phase-1 cross-lane reduce deferred
// to the end. Phase-2 W-write vectorized from the f16 stash. After the main
// loops, the block zeroes the upper-triangle columns of its own 128 rows
// (anti-balanced with attention work: light-qt blocks get most zeros).
__global__ __launch_bounds__(256) void k_attn(const f16* __restrict__ qk16,
                                              const f16* __restrict__ vT,
                                              float* __restrict__ wts,
                                              f16* __restrict__ ctx) {
  const int wgid = blockIdx.x;
  const int xcd = wgid & 7, slot = wgid >> 3;
  const int bh = xcd + 8 * (slot >> 4);
  const int qt = 15 - (slot & 15);  // heavy tiles first within each bh
  const int b = bh >> 4, h = bh & 15;
  const int tid = threadIdx.x, wv = tid >> 6, lane = tid & 63;
  const int lr = lane & 15, lg = lane >> 4;
  const f16* Qb = qk16 + ((long)b * Sn + qt * 128) * LDQK + h * DH;
  const f16* Kb = qk16 + (long)b * Sn * LDQK + Dn + h * DH;
  const f16* Vb = vT + (long)h * DH * MROWS + (long)b * Sn;
  float* Wrow = wts + (long)bh * Sn * Sn + (long)qt * 128 * Sn;
  __shared__ __align__(16) f16 sK[2][128 * 128];  // ping-pong K tiles (Q boot in sK[0])
  __shared__ __align__(16) f16 sQW[128 * 64];     // wave-private P (f16) stash

  // per-thread K-prefetch mapping: 8 chunks of 16B cover 128x128 f16
  const int krr = tid >> 4;          // 0..15
  const int kce = (tid & 15) * 8;    // f16 col
  const int kcb = kce * 2;           // byte col
  f16x8 kpf[8];

#define PRE_K(kt_)                                                              \
  {                                                                             \
    const long kbase = (long)(kt_)*128;                                         \
    _Pragma("unroll") for (int ch = 0; ch < 8; ++ch) kpf[ch] =                  \
        *(const f16x8*)(Kb + (kbase + ch * 16 + krr) * LDQK + kce);             \
  }
#define PUB_K(buf)                                                              \
  {                                                                             \
    _Pragma("unroll") for (int ch = 0; ch < 8; ++ch) {                          \
      const int r = ch * 16 + krr;                                              \
      *(f16x8*)((char*)(buf) + r * 256 + (kcb ^ ((r & 7) << 4))) = kpf[ch];     \
    }                                                                           \
  }

  // ---- prologue: Q through sK[0], K tile 0 into regs ----
  stage_tile128(Qb, LDQK, sK[0]);
  PRE_K(0);
  __syncthreads();
  const int wq0 = wv * 32;
  f16x8 qf[2][4];
#pragma unroll
  for (int m = 0; m < 2; ++m)
#pragma unroll
    for (int kk = 0; kk < 4; ++kk)
      qf[m][kk] = ldfrag128(sK[0], wq0 + m * 16 + lr, kk * 32 + lg * 8);
  __syncthreads();  // all waves done reading Q from sK[0]
  PUB_K(sK[0]);
  if (qt > 0) PRE_K(1);
  __syncthreads();
  int cur = 0;

  // ---- phase 1: causal row sums of exp2(s'); per-lane partials, reduce once ----
  float rs[2][4] = {};
  for (int kt = 0; kt <= qt; ++kt) {
    f32x4 acc[2][8] = {};
#pragma unroll
    for (int kk = 0; kk < 4; ++kk) {
      f16x8 bf[8];
#pragma unroll
      for (int n = 0; n < 8; ++n) bf[n] = ldfrag128(sK[cur], n * 16 + lr, kk * 32 + lg * 8);
#pragma unroll
      for (int m = 0; m < 2; ++m)
#pragma unroll
        for (int n = 0; n < 8; ++n) acc[m][n] = MFMA(qf[m][kk], bf[n], acc[m][n]);
    }
    // publish next tile into the other buffer (overlaps other waves' MFMA)
    if (kt + 1 <= qt) PUB_K(sK[cur ^ 1]);
    PRE_K(kt + 2 <= qt ? kt + 2 : 0);  // tail preloads tile 0 for phase 2
    const bool diag = (kt == qt);
#pragma unroll
    for (int m = 0; m < 2; ++m)
#pragma unroll
      for (int r = 0; r < 4; ++r) {
        const int row = wq0 + m * 16 + lg * 4 + r;
        float ts = 0.f;
#pragma unroll
        for (int n = 0; n < 8; ++n) {
          const bool ok = !diag || (n * 16 + lr) <= row;
          ts += ok ? __builtin_amdgcn_exp2f(acc[m][n][r]) : 0.f;
        }
        rs[m][r] += ts;  // per-lane partial; cross-lane reduce deferred
      }
    __syncthreads();
    cur ^= 1;
  }
  float ri[2][4];
#pragma unroll
  for (int m = 0; m < 2; ++m)
#pragma unroll
    for (int r = 0; r < 4; ++r) {
      float s = rs[m][r];
#pragma unroll
      for (int o = 1; o < 16; o <<= 1) s += __shfl_xor(s, o, 64);
      ri[m][r] = 1.f / s;
    }

  // ---- phase 2 prologue: kpf holds tile 0 ----
  PUB_K(sK[cur ^ 1]);
  if (qt > 0) PRE_K(1);
  __syncthreads();
  cur ^= 1;

  // ---- phase 2: recompute QK, normalize->stash f16, vector W-write, PV ----
  const int ro = lane >> 3, cg = lane & 7;  // W-write mapping: 8 rows x 8 col-groups
  f32x4 pacc[2][8] = {};
  for (int kt = 0; kt <= qt; ++kt) {
    f32x4 sacc[2][8] = {};
#pragma unroll
    for (int kk = 0; kk < 4; ++kk) {
      f16x8 bf[8];
#pragma unroll
      for (int n = 0; n < 8; ++n) bf[n] = ldfrag128(sK[cur], n * 16 + lr, kk * 32 + lg * 8);
#pragma unroll
      for (int m = 0; m < 2; ++m)
#pragma unroll
        for (int n = 0; n < 8; ++n) sacc[m][n] = MFMA(qf[m][kk], bf[n], sacc[m][n]);
    }
    if (kt + 1 <= qt) PUB_K(sK[cur ^ 1]);
    if (kt + 2 <= qt) PRE_K(kt + 2);
    const bool diag = (kt == qt);
    // two 64-col halves: normalize -> f16 stash -> vectorized W write -> PV half
#pragma unroll
    for (int hf = 0; hf < 2; ++hf) {
#pragma unroll
      for (int m = 0; m < 2; ++m)
#pragma unroll
        for (int n = hf * 4; n < hf * 4 + 4; ++n) {
          const int col = n * 16 + lr;
          const int scol = col - hf * 64;
#pragma unroll
          for (int r = 0; r < 4; ++r) {
            const int row = wq0 + m * 16 + lg * 4 + r;
            float w = __builtin_amdgcn_exp2f(sacc[m][n][r]) * ri[m][r];
            if (diag && col > row) w = 0.f;
            *(f16*)((char*)sQW + row * 128 + ((scol * 2) ^ ((row & 7) << 4))) = (f16)w;
          }
        }
      // vectorized W write from the wave-private stash (coalesced 256B rows)
#pragma unroll
      for (int it = 0; it < 4; ++it) {
        const int row = wq0 + it * 8 + ro;
        f16x8 v = ldfrag64(sQW, row, cg * 8);
        f32x4 lo = {(float)v[0], (float)v[1], (float)v[2], (float)v[3]};
        f32x4 hi = {(float)v[4], (float)v[5], (float)v[6], (float)v[7]};
        float* wp = Wrow + (long)row * Sn + kt * 128 + hf * 64 + cg * 8;
        nt_store4(wp, lo);
        nt_store4(wp + 4, hi);
      }
      // PV accumulate over this 64-key half (sQW rows wave-private, no barrier)
#pragma unroll
      for (int kk = 0; kk < 2; ++kk) {
        f16x8 af[2], bfr[8];
#pragma unroll
        for (int m = 0; m < 2; ++m)
          af[m] = ldfrag64(sQW, wq0 + m * 16 + lr, kk * 32 + lg * 8);
#pragma unroll
        for (int n = 0; n < 8; ++n)
          bfr[n] = *(const f16x8*)(Vb + (long)(n * 16 + lr) * MROWS + kt * 128 + hf * 64 + kk * 32 + lg * 8);
#pragma unroll
        for (int m = 0; m < 2; ++m)
#pragma unroll
          for (int n = 0; n < 8; ++n) pacc[m][n] = MFMA(af[m], bfr[n], pacc[m][n]);
      }
    }
    __syncthreads();
    cur ^= 1;
  }

  // ctx epilogue
#pragma unroll
  for (int m = 0; m < 2; ++m)
#pragma unroll
    for (int n = 0; n < 8; ++n) {
      const int d = n * 16 + lr;
#pragma unroll
      for (int r = 0; r < 4; ++r) {
        const int q = qt * 128 + wq0 + m * 16 + lg * 4 + r;
        ctx[(long)(b * Sn + q) * Dn + h * DH + d] = (f16)pacc[m][n][r];
      }
    }

  // ---- upper-triangle zero fill for this block's own 128 rows ----
  // cols [(qt+1)*128, 2048); anti-balanced with the attention work above.
  {
    const int ncols = Sn - (qt + 1) * 128;
    if (ncols > 0) {
      float* base = Wrow + (qt + 1) * 128;
      const f32x4 z = {0.f, 0.f, 0.f, 0.f};
      for (int r = 0; r < 128; ++r) {
        float* rowp = base + (long)r * Sn;
        for (int c = tid * 4; c < ncols; c += 1024) nt_store4(rowp + c, z);
      }
    }
  }
#undef PRE_K
#undef PUB_K
}

extern "C" void kernel_launch(void* const* d_in, const int* in_sizes, int n_in,
                              void* d_out, int out_size, void* d_ws, size_t ws_size,
                              hipStream_t stream) {
  const float* hid = (const float*)d_in[0];
  const float* wq = (const float*)d_in[1];
  const float* wk = (const float*)d_in[2];
  const float* wv = (const float*)d_in[3];
  const float* wo = (const float*)d_in[4];
  const float* bo = (const float*)d_in[5];
  float* out = (float*)d_out;
  float* wts = out + (long)Bc * Sn * Dn;  // attn_weights region: [64][2048][2048] fp32

  char* ws = (char*)d_ws;
  const long MB = 1 << 20;
  f16* h16 = (f16*)(ws + 0 * MB);       // 32 MB
  f16* wqk16 = (f16*)(ws + 32 * MB);    // 16 MB ([wq; wk] rows)
  f16* wv16 = (f16*)(ws + 48 * MB);     // 8 MB
  f16* wo16 = (f16*)(ws + 56 * MB);     // 8 MB
  f16* qk16 = (f16*)(ws + 64 * MB);     // 64 MB  [8192 x 4096] (q | k)
  f16* vT = (f16*)(ws + 128 * MB);      // 32 MB
  f16* ctx = (f16*)(ws + 160 * MB);     // 32 MB

  // all converts, one launch
  k_cvt_all<<<dim3(4096, 8), 256, 0, stream>>>(
      hid, wq, wk, wv, wo, h16, wqk16, wv16, wo16);
  // qk-GEMM (q scaled by log2e) + vT-GEMM, one launch (pure GEMM)
  k_fused<<<3072, 256, 0, stream>>>(h16, wqk16, wv16, qk16, vT);
  // fused attention: stats + recompute + weight write + PV + own-row zfill
  k_attn<<<1024, 256, 0, stream>>>(qk16, vT, wts, ctx);
  // out = ctx @ wo^T + bo
  k_gemm_wo<<<dim3(16, 64), 256, 0, stream>>>(ctx, wo16, out, bo);
}